// Round 23
// baseline (98.895 us; speedup 1.0000x reference)
//
#include <hip/hip_runtime.h>
#include <cstring>
#include <cstdint>

#define TGT 2048
#define NH 16
#define HD 64
#define DIM 1024
#define OD3 3072

typedef _Float16 f16x8 __attribute__((ext_vector_type(8)));
typedef _Float16 f16x4 __attribute__((ext_vector_type(4)));
typedef _Float16 f16x2 __attribute__((ext_vector_type(2)));
typedef float f32x4 __attribute__((ext_vector_type(4)));

__device__ __forceinline__ void gload16(const void* g, void* l) {
  __builtin_amdgcn_global_load_lds(
      (const __attribute__((address_space(1))) unsigned int*)g,
      (__attribute__((address_space(3))) unsigned int*)l, 16, 0, 0);
}

// ---------------- fused cast f32 -> f16 (x, W_in, W_out), 8 elems/thread ----------------
__global__ void cast_all(const float* __restrict__ x, const float* __restrict__ win,
                         const float* __restrict__ wout, _Float16* __restrict__ xh,
                         _Float16* __restrict__ winh, _Float16* __restrict__ wouth) {
  const int NX = TGT * DIM / 8, NW = OD3 * DIM / 8, NO = DIM * DIM / 8;
  int i = blockIdx.x * blockDim.x + threadIdx.x;
  const float* src;
  _Float16* dst;
  int off;
  if (i < NX) { src = x; dst = xh; off = i; }
  else if (i < NX + NW) { src = win; dst = winh; off = i - NX; }
  else if (i < NX + NW + NO) { src = wout; dst = wouth; off = i - NX - NW; }
  else return;
  const float4* p = (const float4*)(src + (size_t)off * 8);
  float4 a = p[0], b = p[1];
  f16x8 o;
  o[0] = (_Float16)a.x; o[1] = (_Float16)a.y; o[2] = (_Float16)a.z; o[3] = (_Float16)a.w;
  o[4] = (_Float16)b.x; o[5] = (_Float16)b.y; o[6] = (_Float16)b.z; o[7] = (_Float16)b.w;
  *(f16x8*)(dst + (size_t)off * 8) = o;
}

// ---------------- QKV GEMM: 128x128 tiles, 384 blocks, 2-D XCD L2 partition -----------
// q -> qh[h][n][64].
// K -> conflict-free fragment tiles: kt=krow>>6; blk=((krow&63)>>4)*2+(d>>5);
//      ln=(krow&15)+16*((d>>3)&3); off = kt*4096 + (blk*64+ln)*8 + (d&7)
// V -> kappa-permuted rows (PV B-frag lane-local in attn):
//      k=krow&63: ks=k>>5, g=(k>>2)&3, e=4*((k>>4)&1)+(k&3)
//      off = kt*4096 + ((np*2+ks)*64 + (d&15) + 16*g)*8 + e   (np=d>>4)
__global__ __launch_bounds__(256, 3) void gemm_qkv(
    const _Float16* __restrict__ A, const _Float16* __restrict__ B,
    _Float16* __restrict__ qh, _Float16* __restrict__ kg, _Float16* __restrict__ vg) {
  __shared__ __attribute__((aligned(16))) _Float16 As[2][4096];
  __shared__ __attribute__((aligned(16))) _Float16 Bs[2][4096];
  const int tid = threadIdx.x, lane = tid & 63, w = tid >> 6;
  const int g = lane >> 4, c = lane & 15;
  const int wr = w >> 1, wc = w & 1;
  const int id = blockIdx.x;               // 384 blocks
  const int xcd = id & 7, r = id >> 3;     // r: 0..47
  const int mh = xcd & 1, nq = xcd >> 1;
  const int bm = mh * 1024 + (r / 6) * 128;  // 8 bm-tiles per XCD (A-slice 2MB)
  const int bn = nq * 768 + (r % 6) * 128;   // 6 bn-tiles per XCD (B-slice 1.5MB)
  f32x4 acc[4][4] = {};

#define QKV_STAGE(buf, k0)                                                              \
  {                                                                                     \
    _Pragma("unroll") for (int t = 0; t < 2; ++t) {                                     \
      gload16(A + (size_t)(bm + t * 64 + lane) * DIM + (k0) + w * 8,                    \
              &As[buf][w * 1024 + t * 512]);                                            \
      gload16(B + (size_t)(bn + t * 64 + lane) * DIM + (k0) + w * 8,                    \
              &Bs[buf][w * 1024 + t * 512]);                                            \
    }                                                                                   \
  }

  QKV_STAGE(0, 0);
  __syncthreads();
  for (int kk = 0; kk < 32; ++kk) {
    const int cur = kk & 1;
    if (kk + 1 < 32) QKV_STAGE(cur ^ 1, (kk + 1) * 32);
    f16x8 af[4], bf[4];
#pragma unroll
    for (int m = 0; m < 4; ++m) af[m] = *(const f16x8*)(&As[cur][g * 1024 + (wr * 64 + m * 16 + c) * 8]);
#pragma unroll
    for (int n = 0; n < 4; ++n) bf[n] = *(const f16x8*)(&Bs[cur][g * 1024 + (wc * 64 + n * 16 + c) * 8]);
    __builtin_amdgcn_s_setprio(1);
#pragma unroll
    for (int m = 0; m < 4; ++m)
#pragma unroll
      for (int n = 0; n < 4; ++n)
        acc[m][n] = __builtin_amdgcn_mfma_f32_16x16x32_f16(af[m], bf[n], acc[m][n], 0, 0, 0);
    __builtin_amdgcn_s_setprio(0);
    __syncthreads();
  }
#undef QKV_STAGE

  const int which = bn >> 10;  // 0=q 1=k 2=v (uniform per block)
  const int bnn = bn & 1023;
  if (which == 0) {
#pragma unroll
    for (int m = 0; m < 4; ++m)
#pragma unroll
      for (int n = 0; n < 4; ++n)
#pragma unroll
        for (int j = 0; j < 4; ++j) {
          int row = bm + wr * 64 + m * 16 + g * 4 + j;
          int o = bnn + wc * 64 + n * 16 + c;
          qh[((size_t)(o >> 6) * TGT + row) * HD + (o & 63)] = (_Float16)acc[m][n][j];
        }
  } else if (which == 1) {
#pragma unroll
    for (int m = 0; m < 4; ++m)
#pragma unroll
      for (int n = 0; n < 4; ++n)
#pragma unroll
        for (int j = 0; j < 4; ++j) {
          int krow = bm + wr * 64 + m * 16 + g * 4 + j;
          int o = bnn + wc * 64 + n * 16 + c;
          int hh = o >> 6, d = o & 63;
          int kt = krow >> 6, rr = krow & 63;
          int blk = (rr >> 4) * 2 + (d >> 5);
          int ln = (rr & 15) + 16 * ((d >> 3) & 3);
          kg[(size_t)hh * 131072 + kt * 4096 + (blk * 64 + ln) * 8 + (d & 7)] =
              (_Float16)acc[m][n][j];
        }
  } else {
#pragma unroll
    for (int m = 0; m < 4; ++m)
#pragma unroll
      for (int n = 0; n < 4; ++n) {
        int krow0 = bm + wr * 64 + m * 16 + g * 4;  // j = 0..3 consecutive k-rows
        int o = bnn + wc * 64 + n * 16 + c;
        int hh = o >> 6, d = o & 63;
        int kt = krow0 >> 6, k = krow0 & 63;
        int np = d >> 4, cc = d & 15;
        int ks2 = k >> 5, gg = (k >> 2) & 3, e0 = 4 * ((k >> 4) & 1);
        f16x4 v;
#pragma unroll
        for (int j = 0; j < 4; ++j) v[j] = (_Float16)acc[m][n][j];
        *(f16x4*)(vg + (size_t)hh * 131072 + kt * 4096 +
                  ((np * 2 + ks2) * 64 + cc + 16 * gg) * 8 + e0) = v;
      }
  }
}

// ---------------- out GEMM: 64x64 tiles, 512 blocks, 2-D XCD L2 partition -------------
__global__ __launch_bounds__(256, 2) void gemm_out(
    const _Float16* __restrict__ A, const _Float16* __restrict__ B, float* __restrict__ out) {
  __shared__ __attribute__((aligned(16))) _Float16 As[2][2048];
  __shared__ __attribute__((aligned(16))) _Float16 Bs[2][2048];
  const int tid = threadIdx.x, lane = tid & 63, w = tid >> 6;
  const int g = lane >> 4, c = lane & 15;
  const int wr = w >> 1, wc = w & 1;
  const int id = blockIdx.x;               // 512 blocks
  const int xcd = id & 7, r = id >> 3;     // r: 0..63
  const int mh = xcd & 1, nq = xcd >> 1;
  const int bm = mh * 1024 + (r / 4) * 64; // 16 bm-groups per XCD (A-slice 2MB)
  const int bn = nq * 256 + (r % 4) * 64;  // 4 bn-groups per XCD (B-slice 0.5MB)
  f32x4 acc[2][2] = {};

#define OUT_STAGE(buf, k0)                                                              \
  {                                                                                     \
    gload16(A + (size_t)(bm + (tid & 63)) * DIM + (k0) + (tid >> 6) * 8,                \
            &As[buf][tid * 8]);                                                         \
    gload16(B + (size_t)(bn + (tid & 63)) * DIM + (k0) + (tid >> 6) * 8,                \
            &Bs[buf][tid * 8]);                                                         \
  }

  OUT_STAGE(0, 0);
  __syncthreads();
  for (int kk = 0; kk < 32; ++kk) {
    const int cur = kk & 1;
    if (kk + 1 < 32) OUT_STAGE(cur ^ 1, (kk + 1) * 32);
    f16x8 af[2], bf[2];
#pragma unroll
    for (int m = 0; m < 2; ++m) af[m] = *(const f16x8*)(&As[cur][g * 512 + (wr * 32 + m * 16 + c) * 8]);
#pragma unroll
    for (int n = 0; n < 2; ++n) bf[n] = *(const f16x8*)(&Bs[cur][g * 512 + (wc * 32 + n * 16 + c) * 8]);
    __builtin_amdgcn_s_setprio(1);
#pragma unroll
    for (int m = 0; m < 2; ++m)
#pragma unroll
      for (int n = 0; n < 2; ++n)
        acc[m][n] = __builtin_amdgcn_mfma_f32_16x16x32_f16(af[m], bf[n], acc[m][n], 0, 0, 0);
    __builtin_amdgcn_s_setprio(0);
    __syncthreads();
  }
#undef OUT_STAGE

#pragma unroll
  for (int m = 0; m < 2; ++m)
#pragma unroll
    for (int n = 0; n < 2; ++n)
#pragma unroll
      for (int j = 0; j < 4; ++j) {
        int row = bm + wr * 32 + m * 16 + g * 4 + j;
        int o = bn + wc * 32 + n * 16 + c;
        out[(size_t)row * DIM + o] = acc[m][n][j];
      }
}

// ---------------- flash attention: K staged in LDS, V DIRECT from L2 ------------------
// In-block split-K x2 (2 groups of 4 waves). V rows kappa-permuted -> each PV B-frag is
// a per-lane-contiguous 16B global load (coalesced, L2-resident); LDS halves to 32KB.
// Flat grid 512, 2 heads pinned per XCD: per-XCD K+V working set = 1MB (L2-fits).
__global__ __launch_bounds__(512, 4) void attn(
    const _Float16* __restrict__ qh, const _Float16* __restrict__ kg,
    const _Float16* __restrict__ vg, _Float16* __restrict__ ctxh, float scal2) {
  __shared__ __attribute__((aligned(16))) _Float16 Ks[2][2][4096];  // [grp][buf], 32KB
  const int tid = threadIdx.x;
  const int grp = tid >> 8, t256 = tid & 255;
  const int lane = tid & 63, w = (tid >> 6) & 3;
  const int g = lane >> 4, c = lane & 15;
  const int id = blockIdx.x;                      // 512 blocks
  const int h = (id & 7) * 2 + ((id >> 3) & 1);   // 2 heads per XCD
  const int qblk = id >> 4;                       // 0..31
  const int qrow = qblk * 64 + w * 16 + c;
  const _Float16* kb = kg + (size_t)h * 131072 + (size_t)grp * 65536;
  const _Float16* vb = vg + (size_t)h * 131072 + (size_t)grp * 65536;

  f16x8 qf[2];
#pragma unroll
  for (int ks = 0; ks < 2; ++ks)
    qf[ks] = *(const f16x8*)(qh + ((size_t)h * TGT + qrow) * HD + ks * 32 + g * 8);

  float m2 = -INFINITY, lsum = 0.f;
  f32x4 oacc[4] = {};

#define ATTN_STAGE(buf, kt)                                                         \
  {                                                                                 \
    _Pragma("unroll") for (int t = 0; t < 2; ++t) {                                 \
      int chunk = t * 256 + t256;                                                   \
      gload16(kb + (size_t)(kt) * 4096 + chunk * 8, &Ks[grp][buf][chunk * 8]);      \
    }                                                                               \
  }

  ATTN_STAGE(0, 0);
  __syncthreads();

  for (int kt = 0; kt < 16; ++kt) {
    const int cur = kt & 1;
    if (kt + 1 < 16) ATTN_STAGE(cur ^ 1, kt + 1);

    // S^T = K Q^T : lane holds S[q=c][k = n*16 + g*4 + j], n in [0,4)
    f32x4 s[4] = {};
    __builtin_amdgcn_s_setprio(1);
#pragma unroll
    for (int n = 0; n < 4; ++n)
#pragma unroll
      for (int ks = 0; ks < 2; ++ks) {
        f16x8 kf = *(const f16x8*)(&Ks[grp][cur][((n * 2 + ks) * 64 + lane) * 8]);
        s[n] = __builtin_amdgcn_mfma_f32_16x16x32_f16(kf, qf[ks], s[n], 0, 0, 0);
      }
    __builtin_amdgcn_s_setprio(0);

    // row max: in-lane tree, then across g (xor 16, 32)
    f32x4 m4;
#pragma unroll
    for (int j = 0; j < 4; ++j) m4[j] = fmaxf(fmaxf(s[0][j], s[1][j]), fmaxf(s[2][j], s[3][j]));
    float mx = fmaxf(fmaxf(m4[0], m4[1]), fmaxf(m4[2], m4[3]));
    mx = fmaxf(mx, __shfl_xor(mx, 16));
    mx = fmaxf(mx, __shfl_xor(mx, 32));
    float pmax = mx * scal2;  // log2 domain

    if (!__all(pmax <= m2 + 8.f)) {  // T13 defer-max
      float mnew = fmaxf(m2, pmax);
      float alpha = __builtin_amdgcn_exp2f(m2 - mnew);
      m2 = mnew;
      lsum *= alpha;
#pragma unroll
      for (int np = 0; np < 4; ++np)
#pragma unroll
        for (int j = 0; j < 4; ++j) oacc[np][j] *= alpha;
    }

    // p = exp2(s*scal2 - m2), pack to f16 pairs, accumulate row sum
    float tsum = 0.f;
    uint32_t pk[4][2];
#pragma unroll
    for (int n = 0; n < 4; ++n) {
      float p0 = __builtin_amdgcn_exp2f(__builtin_fmaf(s[n][0], scal2, -m2));
      float p1 = __builtin_amdgcn_exp2f(__builtin_fmaf(s[n][1], scal2, -m2));
      float p2 = __builtin_amdgcn_exp2f(__builtin_fmaf(s[n][2], scal2, -m2));
      float p3 = __builtin_amdgcn_exp2f(__builtin_fmaf(s[n][3], scal2, -m2));
      tsum += (p0 + p1) + (p2 + p3);
      auto a = __builtin_amdgcn_cvt_pkrtz(p0, p1);
      auto b = __builtin_amdgcn_cvt_pkrtz(p2, p3);
      memcpy(&pk[n][0], &a, 4);
      memcpy(&pk[n][1], &b, 4);
    }
    tsum += __shfl_xor(tsum, 16);
    tsum += __shfl_xor(tsum, 32);
    lsum += tsum;

    // PV: ctx^T += W . P; W frags read DIRECT from global (kappa layout => 16B/lane)
#pragma unroll
    for (int ks = 0; ks < 2; ++ks) {
      f16x8 pa;
      memcpy(&pa, &pk[2 * ks][0], 16);
      __builtin_amdgcn_s_setprio(1);
#pragma unroll
      for (int np = 0; np < 4; ++np) {
        f16x8 vbf = *(const f16x8*)(vb + (size_t)kt * 4096 + ((np * 2 + ks) * 64 + lane) * 8);
        oacc[np] = __builtin_amdgcn_mfma_f32_16x16x32_f16(vbf, pa, oacc[np], 0, 0, 0);
      }
      __builtin_amdgcn_s_setprio(0);
    }
    __syncthreads();
  }
#undef ATTN_STAGE

  // ---- in-LDS merge of the two k-halves (scratch reuses Ks) ----
  float* smo = (float*)&Ks[0][0][0];  // 16KB: group1's oacc
  float* sml = (float*)&Ks[1][0][0];  // 2KB: group1's (m, l)
  if (grp == 1) {
#pragma unroll
    for (int np = 0; np < 4; ++np)
#pragma unroll
      for (int j = 0; j < 4; ++j) smo[t256 * 16 + np * 4 + j] = oacc[np][j];
    sml[t256 * 2] = m2;
    sml[t256 * 2 + 1] = lsum;
  }
  __syncthreads();
  if (grp == 0) {
    float m1 = sml[t256 * 2], l1 = sml[t256 * 2 + 1];
    float mm = fmaxf(m2, m1);
    float e0 = __builtin_amdgcn_exp2f(m2 - mm);
    float e1 = __builtin_amdgcn_exp2f(m1 - mm);
    float inv = 1.0f / (lsum * e0 + l1 * e1);
#pragma unroll
    for (int np = 0; np < 4; ++np) {
      f16x4 o4;
#pragma unroll
      for (int j = 0; j < 4; ++j)
        o4[j] = (_Float16)((oacc[np][j] * e0 + smo[t256 * 16 + np * 4 + j] * e1) * inv);
      *(f16x4*)(ctxh + (size_t)qrow * DIM + h * HD + np * 16 + g * 4) = o4;
    }
  }
}

// ---------------- host ----------------
static float fp16_round_host(float x) {
  uint32_t u; memcpy(&u, &x, 4);
  uint32_t sign = u & 0x80000000u;
  uint32_t exp = (u >> 23) & 0xff;
  uint32_t m = u & 0x7fffffu;
  uint32_t low = m & 0x1fffu, hi = m >> 13;
  if (low > 0x1000u || (low == 0x1000u && (hi & 1))) hi++;
  if (hi == 0x400u) { hi = 0; exp++; }
  uint32_t r = sign | (exp << 23) | (hi << 13);
  float f; memcpy(&f, &r, 4); return f;
}

extern "C" void kernel_launch(void* const* d_in, const int* in_sizes, int n_in,
                              void* d_out, int out_size, void* d_ws, size_t ws_size,
                              hipStream_t stream) {
  const float* x = (const float*)d_in[0];
  const float* Win = (const float*)d_in[1];
  const float* Wout = (const float*)d_in[2];
  float* out = (float*)d_out;
  char* ws = (char*)d_ws;
  _Float16* xh    = (_Float16*)(ws);
  _Float16* winh  = (_Float16*)(ws + (4ull << 20));
  _Float16* wouth = (_Float16*)(ws + (10ull << 20));
  _Float16* qh    = (_Float16*)(ws + (12ull << 20));
  _Float16* kg    = (_Float16*)(ws + (16ull << 20));
  _Float16* vg    = (_Float16*)(ws + (20ull << 20));
  _Float16* ctxh  = (_Float16*)(ws + (24ull << 20));

  // Quake fast-rsqrt(64) with one Newton step, fp32 ops in numpy order, then fp16 round.
  float y = 64.0f;
  volatile float x2 = 32.0f;
  int ib; memcpy(&ib, &y, 4);
  ib = 1597463007 - (ib >> 1);
  memcpy(&y, &ib, 4);
  volatile float t1 = x2 * y;
  volatile float t2 = t1 * y;
  volatile float t3 = 1.5f - t2;
  y = y * t3;
  const float scaling = fp16_round_host(y);
  const float scal2 = scaling * 1.4426950408889634f;  // * log2(e)

  const int ncast = (TGT * DIM + OD3 * DIM + DIM * DIM) / 8;
  cast_all<<<(ncast + 255) / 256, 256, 0, stream>>>(x, Win, Wout, xh, winh, wouth);
  gemm_qkv<<<384, 256, 0, stream>>>(xh, winh, qh, kg, vg);
  attn<<<512, 512, 0, stream>>>(qh, kg, vg, ctxh, scal2);
  gemm_out<<<512, 256, 0, stream>>>(ctxh, wouth, out);
}

// Round 24
// 95.655 us; speedup vs baseline: 1.0339x; 1.0339x over previous
//
#include <hip/hip_runtime.h>
#include <cstring>
#include <cstdint>

#define TGT 2048
#define NH 16
#define HD 64
#define DIM 1024
#define OD3 3072

typedef _Float16 f16x8 __attribute__((ext_vector_type(8)));
typedef _Float16 f16x4 __attribute__((ext_vector_type(4)));
typedef _Float16 f16x2 __attribute__((ext_vector_type(2)));
typedef float f32x4 __attribute__((ext_vector_type(4)));

__device__ __forceinline__ void gload16(const void* g, void* l) {
  __builtin_amdgcn_global_load_lds(
      (const __attribute__((address_space(1))) unsigned int*)g,
      (__attribute__((address_space(3))) unsigned int*)l, 16, 0, 0);
}

// ---------------- fused cast f32 -> f16 (x, W_in, W_out), 8 elems/thread ----------------
__global__ void cast_all(const float* __restrict__ x, const float* __restrict__ win,
                         const float* __restrict__ wout, _Float16* __restrict__ xh,
                         _Float16* __restrict__ winh, _Float16* __restrict__ wouth) {
  const int NX = TGT * DIM / 8, NW = OD3 * DIM / 8, NO = DIM * DIM / 8;
  int i = blockIdx.x * blockDim.x + threadIdx.x;
  const float* src;
  _Float16* dst;
  int off;
  if (i < NX) { src = x; dst = xh; off = i; }
  else if (i < NX + NW) { src = win; dst = winh; off = i - NX; }
  else if (i < NX + NW + NO) { src = wout; dst = wouth; off = i - NX - NW; }
  else return;
  const float4* p = (const float4*)(src + (size_t)off * 8);
  float4 a = p[0], b = p[1];
  f16x8 o;
  o[0] = (_Float16)a.x; o[1] = (_Float16)a.y; o[2] = (_Float16)a.z; o[3] = (_Float16)a.w;
  o[4] = (_Float16)b.x; o[5] = (_Float16)b.y; o[6] = (_Float16)b.z; o[7] = (_Float16)b.w;
  *(f16x8*)(dst + (size_t)off * 8) = o;
}

// ---------------- QKV GEMM: 128x128 tiles, 384 blocks, 2-D XCD L2 partition -----------
// q -> qh[h][n][64].
// K -> conflict-free fragment tiles: kt=krow>>6; blk=((krow&63)>>4)*2+(d>>5);
//      ln=(krow&15)+16*((d>>3)&3); off = kt*4096 + (blk*64+ln)*8 + (d&7)
// V -> kappa-permuted rows (PV B-frag lane-local in attn):
//      k=krow&63: ks=k>>5, g=(k>>2)&3, e=4*((k>>4)&1)+(k&3)
//      off = kt*4096 + ((np*2+ks)*64 + (d&15) + 16*g)*8 + e   (np=d>>4)
__global__ __launch_bounds__(256, 3) void gemm_qkv(
    const _Float16* __restrict__ A, const _Float16* __restrict__ B,
    _Float16* __restrict__ qh, _Float16* __restrict__ kg, _Float16* __restrict__ vg) {
  __shared__ __attribute__((aligned(16))) _Float16 As[2][4096];
  __shared__ __attribute__((aligned(16))) _Float16 Bs[2][4096];
  const int tid = threadIdx.x, lane = tid & 63, w = tid >> 6;
  const int g = lane >> 4, c = lane & 15;
  const int wr = w >> 1, wc = w & 1;
  const int id = blockIdx.x;               // 384 blocks
  const int xcd = id & 7, r = id >> 3;     // r: 0..47
  const int mh = xcd & 1, nq = xcd >> 1;
  const int bm = mh * 1024 + (r / 6) * 128;  // 8 bm-tiles per XCD (A-slice 2MB)
  const int bn = nq * 768 + (r % 6) * 128;   // 6 bn-tiles per XCD (B-slice 1.5MB)
  f32x4 acc[4][4] = {};

#define QKV_STAGE(buf, k0)                                                              \
  {                                                                                     \
    _Pragma("unroll") for (int t = 0; t < 2; ++t) {                                     \
      gload16(A + (size_t)(bm + t * 64 + lane) * DIM + (k0) + w * 8,                    \
              &As[buf][w * 1024 + t * 512]);                                            \
      gload16(B + (size_t)(bn + t * 64 + lane) * DIM + (k0) + w * 8,                    \
              &Bs[buf][w * 1024 + t * 512]);                                            \
    }                                                                                   \
  }

  QKV_STAGE(0, 0);
  __syncthreads();
  for (int kk = 0; kk < 32; ++kk) {
    const int cur = kk & 1;
    if (kk + 1 < 32) QKV_STAGE(cur ^ 1, (kk + 1) * 32);
    f16x8 af[4], bf[4];
#pragma unroll
    for (int m = 0; m < 4; ++m) af[m] = *(const f16x8*)(&As[cur][g * 1024 + (wr * 64 + m * 16 + c) * 8]);
#pragma unroll
    for (int n = 0; n < 4; ++n) bf[n] = *(const f16x8*)(&Bs[cur][g * 1024 + (wc * 64 + n * 16 + c) * 8]);
    __builtin_amdgcn_s_setprio(1);
#pragma unroll
    for (int m = 0; m < 4; ++m)
#pragma unroll
      for (int n = 0; n < 4; ++n)
        acc[m][n] = __builtin_amdgcn_mfma_f32_16x16x32_f16(af[m], bf[n], acc[m][n], 0, 0, 0);
    __builtin_amdgcn_s_setprio(0);
    __syncthreads();
  }
#undef QKV_STAGE

  const int which = bn >> 10;  // 0=q 1=k 2=v (uniform per block)
  const int bnn = bn & 1023;
  if (which == 0) {
#pragma unroll
    for (int m = 0; m < 4; ++m)
#pragma unroll
      for (int n = 0; n < 4; ++n)
#pragma unroll
        for (int j = 0; j < 4; ++j) {
          int row = bm + wr * 64 + m * 16 + g * 4 + j;
          int o = bnn + wc * 64 + n * 16 + c;
          qh[((size_t)(o >> 6) * TGT + row) * HD + (o & 63)] = (_Float16)acc[m][n][j];
        }
  } else if (which == 1) {
#pragma unroll
    for (int m = 0; m < 4; ++m)
#pragma unroll
      for (int n = 0; n < 4; ++n)
#pragma unroll
        for (int j = 0; j < 4; ++j) {
          int krow = bm + wr * 64 + m * 16 + g * 4 + j;
          int o = bnn + wc * 64 + n * 16 + c;
          int hh = o >> 6, d = o & 63;
          int kt = krow >> 6, rr = krow & 63;
          int blk = (rr >> 4) * 2 + (d >> 5);
          int ln = (rr & 15) + 16 * ((d >> 3) & 3);
          kg[(size_t)hh * 131072 + kt * 4096 + (blk * 64 + ln) * 8 + (d & 7)] =
              (_Float16)acc[m][n][j];
        }
  } else {
#pragma unroll
    for (int m = 0; m < 4; ++m)
#pragma unroll
      for (int n = 0; n < 4; ++n) {
        int krow0 = bm + wr * 64 + m * 16 + g * 4;  // j = 0..3 consecutive k-rows
        int o = bnn + wc * 64 + n * 16 + c;
        int hh = o >> 6, d = o & 63;
        int kt = krow0 >> 6, k = krow0 & 63;
        int np = d >> 4, cc = d & 15;
        int ks2 = k >> 5, gg = (k >> 2) & 3, e0 = 4 * ((k >> 4) & 1);
        f16x4 v;
#pragma unroll
        for (int j = 0; j < 4; ++j) v[j] = (_Float16)acc[m][n][j];
        *(f16x4*)(vg + (size_t)hh * 131072 + kt * 4096 +
                  ((np * 2 + ks2) * 64 + cc + 16 * gg) * 8 + e0) = v;
      }
  }
}

// ---------------- out GEMM: 64x64 tiles, 512 blocks, 2-D XCD L2 partition -------------
__global__ __launch_bounds__(256, 2) void gemm_out(
    const _Float16* __restrict__ A, const _Float16* __restrict__ B, float* __restrict__ out) {
  __shared__ __attribute__((aligned(16))) _Float16 As[2][2048];
  __shared__ __attribute__((aligned(16))) _Float16 Bs[2][2048];
  const int tid = threadIdx.x, lane = tid & 63, w = tid >> 6;
  const int g = lane >> 4, c = lane & 15;
  const int wr = w >> 1, wc = w & 1;
  const int id = blockIdx.x;               // 512 blocks
  const int xcd = id & 7, r = id >> 3;     // r: 0..63
  const int mh = xcd & 1, nq = xcd >> 1;
  const int bm = mh * 1024 + (r / 4) * 64; // 16 bm-groups per XCD (A-slice 2MB)
  const int bn = nq * 256 + (r % 4) * 64;  // 4 bn-groups per XCD (B-slice 0.5MB)
  f32x4 acc[2][2] = {};

#define OUT_STAGE(buf, k0)                                                              \
  {                                                                                     \
    gload16(A + (size_t)(bm + (tid & 63)) * DIM + (k0) + (tid >> 6) * 8,                \
            &As[buf][tid * 8]);                                                         \
    gload16(B + (size_t)(bn + (tid & 63)) * DIM + (k0) + (tid >> 6) * 8,                \
            &Bs[buf][tid * 8]);                                                         \
  }

  OUT_STAGE(0, 0);
  __syncthreads();
  for (int kk = 0; kk < 32; ++kk) {
    const int cur = kk & 1;
    if (kk + 1 < 32) OUT_STAGE(cur ^ 1, (kk + 1) * 32);
    f16x8 af[2], bf[2];
#pragma unroll
    for (int m = 0; m < 2; ++m) af[m] = *(const f16x8*)(&As[cur][g * 512 + (wr * 32 + m * 16 + c) * 8]);
#pragma unroll
    for (int n = 0; n < 2; ++n) bf[n] = *(const f16x8*)(&Bs[cur][g * 512 + (wc * 32 + n * 16 + c) * 8]);
    __builtin_amdgcn_s_setprio(1);
#pragma unroll
    for (int m = 0; m < 2; ++m)
#pragma unroll
      for (int n = 0; n < 2; ++n)
        acc[m][n] = __builtin_amdgcn_mfma_f32_16x16x32_f16(af[m], bf[n], acc[m][n], 0, 0, 0);
    __builtin_amdgcn_s_setprio(0);
    __syncthreads();
  }
#undef OUT_STAGE

#pragma unroll
  for (int m = 0; m < 2; ++m)
#pragma unroll
    for (int n = 0; n < 2; ++n)
#pragma unroll
      for (int j = 0; j < 4; ++j) {
        int row = bm + wr * 32 + m * 16 + g * 4 + j;
        int o = bn + wc * 32 + n * 16 + c;
        out[(size_t)row * DIM + o] = acc[m][n][j];
      }
}

// ---------------- flash attention: K in LDS, V direct-to-register ISSUED EARLY --------
// T14 issue-early: all 8 V frags for tile kt load into registers at the TOP of the
// iteration; QK^T + softmax (~350 cyc) cover their L2 latency; PV consumes registers.
// In-block split-K x2; 2 heads pinned per XCD (K+V = 1MB, L2-resident); LDS 32KB.
__global__ __launch_bounds__(512, 4) void attn(
    const _Float16* __restrict__ qh, const _Float16* __restrict__ kg,
    const _Float16* __restrict__ vg, _Float16* __restrict__ ctxh, float scal2) {
  __shared__ __attribute__((aligned(16))) _Float16 Ks[2][2][4096];  // [grp][buf], 32KB
  const int tid = threadIdx.x;
  const int grp = tid >> 8, t256 = tid & 255;
  const int lane = tid & 63, w = (tid >> 6) & 3;
  const int g = lane >> 4, c = lane & 15;
  const int id = blockIdx.x;                      // 512 blocks
  const int h = (id & 7) * 2 + ((id >> 3) & 1);   // 2 heads per XCD
  const int qblk = id >> 4;                       // 0..31
  const int qrow = qblk * 64 + w * 16 + c;
  const _Float16* kb = kg + (size_t)h * 131072 + (size_t)grp * 65536;
  const _Float16* vb = vg + (size_t)h * 131072 + (size_t)grp * 65536 + (size_t)lane * 8;

  f16x8 qf[2];
#pragma unroll
  for (int ks = 0; ks < 2; ++ks)
    qf[ks] = *(const f16x8*)(qh + ((size_t)h * TGT + qrow) * HD + ks * 32 + g * 8);

  float m2 = -INFINITY, lsum = 0.f;
  f32x4 oacc[4] = {};

#define ATTN_STAGE(buf, kt)                                                         \
  {                                                                                 \
    _Pragma("unroll") for (int t = 0; t < 2; ++t) {                                 \
      int chunk = t * 256 + t256;                                                   \
      gload16(kb + (size_t)(kt) * 4096 + chunk * 8, &Ks[grp][buf][chunk * 8]);      \
    }                                                                               \
  }

  ATTN_STAGE(0, 0);
  __syncthreads();

  for (int kt = 0; kt < 16; ++kt) {
    const int cur = kt & 1;
    if (kt + 1 < 16) ATTN_STAGE(cur ^ 1, kt + 1);

    // T14 issue-early: V fragments for THIS tile, loaded before QK^T + softmax.
    f16x8 vfr[2][4];
#pragma unroll
    for (int ks = 0; ks < 2; ++ks)
#pragma unroll
      for (int np = 0; np < 4; ++np)
        vfr[ks][np] = *(const f16x8*)(vb + (size_t)kt * 4096 + (np * 2 + ks) * 512);

    // S^T = K Q^T : lane holds S[q=c][k = n*16 + g*4 + j], n in [0,4)
    f32x4 s[4] = {};
    __builtin_amdgcn_s_setprio(1);
#pragma unroll
    for (int n = 0; n < 4; ++n)
#pragma unroll
      for (int ks = 0; ks < 2; ++ks) {
        f16x8 kf = *(const f16x8*)(&Ks[grp][cur][((n * 2 + ks) * 64 + lane) * 8]);
        s[n] = __builtin_amdgcn_mfma_f32_16x16x32_f16(kf, qf[ks], s[n], 0, 0, 0);
      }
    __builtin_amdgcn_s_setprio(0);

    // row max: in-lane tree, then across g (xor 16, 32)
    f32x4 m4;
#pragma unroll
    for (int j = 0; j < 4; ++j) m4[j] = fmaxf(fmaxf(s[0][j], s[1][j]), fmaxf(s[2][j], s[3][j]));
    float mx = fmaxf(fmaxf(m4[0], m4[1]), fmaxf(m4[2], m4[3]));
    mx = fmaxf(mx, __shfl_xor(mx, 16));
    mx = fmaxf(mx, __shfl_xor(mx, 32));
    float pmax = mx * scal2;  // log2 domain

    if (!__all(pmax <= m2 + 8.f)) {  // T13 defer-max
      float mnew = fmaxf(m2, pmax);
      float alpha = __builtin_amdgcn_exp2f(m2 - mnew);
      m2 = mnew;
      lsum *= alpha;
#pragma unroll
      for (int np = 0; np < 4; ++np)
#pragma unroll
        for (int j = 0; j < 4; ++j) oacc[np][j] *= alpha;
    }

    // p = exp2(s*scal2 - m2), pack to f16 pairs, accumulate row sum
    float tsum = 0.f;
    uint32_t pk[4][2];
#pragma unroll
    for (int n = 0; n < 4; ++n) {
      float p0 = __builtin_amdgcn_exp2f(__builtin_fmaf(s[n][0], scal2, -m2));
      float p1 = __builtin_amdgcn_exp2f(__builtin_fmaf(s[n][1], scal2, -m2));
      float p2 = __builtin_amdgcn_exp2f(__builtin_fmaf(s[n][2], scal2, -m2));
      float p3 = __builtin_amdgcn_exp2f(__builtin_fmaf(s[n][3], scal2, -m2));
      tsum += (p0 + p1) + (p2 + p3);
      auto a = __builtin_amdgcn_cvt_pkrtz(p0, p1);
      auto b = __builtin_amdgcn_cvt_pkrtz(p2, p3);
      memcpy(&pk[n][0], &a, 4);
      memcpy(&pk[n][1], &b, 4);
    }
    tsum += __shfl_xor(tsum, 16);
    tsum += __shfl_xor(tsum, 32);
    lsum += tsum;

    // PV: ctx^T += W . P ; W frags already in registers (loaded at top of iteration)
#pragma unroll
    for (int ks = 0; ks < 2; ++ks) {
      f16x8 pa;
      memcpy(&pa, &pk[2 * ks][0], 16);
      __builtin_amdgcn_s_setprio(1);
#pragma unroll
      for (int np = 0; np < 4; ++np)
        oacc[np] = __builtin_amdgcn_mfma_f32_16x16x32_f16(vfr[ks][np], pa, oacc[np], 0, 0, 0);
      __builtin_amdgcn_s_setprio(0);
    }
    __syncthreads();
  }
#undef ATTN_STAGE

  // ---- in-LDS merge of the two k-halves (scratch reuses Ks) ----
  float* smo = (float*)&Ks[0][0][0];  // 16KB: group1's oacc
  float* sml = (float*)&Ks[1][0][0];  // 2KB: group1's (m, l)
  if (grp == 1) {
#pragma unroll
    for (int np = 0; np < 4; ++np)
#pragma unroll
      for (int j = 0; j < 4; ++j) smo[t256 * 16 + np * 4 + j] = oacc[np][j];
    sml[t256 * 2] = m2;
    sml[t256 * 2 + 1] = lsum;
  }
  __syncthreads();
  if (grp == 0) {
    float m1 = sml[t256 * 2], l1 = sml[t256 * 2 + 1];
    float mm = fmaxf(m2, m1);
    float e0 = __builtin_amdgcn_exp2f(m2 - mm);
    float e1 = __builtin_amdgcn_exp2f(m1 - mm);
    float inv = 1.0f / (lsum * e0 + l1 * e1);
#pragma unroll
    for (int np = 0; np < 4; ++np) {
      f16x4 o4;
#pragma unroll
      for (int j = 0; j < 4; ++j)
        o4[j] = (_Float16)((oacc[np][j] * e0 + smo[t256 * 16 + np * 4 + j] * e1) * inv);
      *(f16x4*)(ctxh + (size_t)qrow * DIM + h * HD + np * 16 + g * 4) = o4;
    }
  }
}

// ---------------- host ----------------
static float fp16_round_host(float x) {
  uint32_t u; memcpy(&u, &x, 4);
  uint32_t sign = u & 0x80000000u;
  uint32_t exp = (u >> 23) & 0xff;
  uint32_t m = u & 0x7fffffu;
  uint32_t low = m & 0x1fffu, hi = m >> 13;
  if (low > 0x1000u || (low == 0x1000u && (hi & 1))) hi++;
  if (hi == 0x400u) { hi = 0; exp++; }
  uint32_t r = sign | (exp << 23) | (hi << 13);
  float f; memcpy(&f, &r, 4); return f;
}

extern "C" void kernel_launch(void* const* d_in, const int* in_sizes, int n_in,
                              void* d_out, int out_size, void* d_ws, size_t ws_size,
                              hipStream_t stream) {
  const float* x = (const float*)d_in[0];
  const float* Win = (const float*)d_in[1];
  const float* Wout = (const float*)d_in[2];
  float* out = (float*)d_out;
  char* ws = (char*)d_ws;
  _Float16* xh    = (_Float16*)(ws);
  _Float16* winh  = (_Float16*)(ws + (4ull << 20));
  _Float16* wouth = (_Float16*)(ws + (10ull << 20));
  _Float16* qh    = (_Float16*)(ws + (12ull << 20));
  _Float16* kg    = (_Float16*)(ws + (16ull << 20));
  _Float16* vg    = (_Float16*)(ws + (20ull << 20));
  _Float16* ctxh  = (_Float16*)(ws + (24ull << 20));

  // Quake fast-rsqrt(64) with one Newton step, fp32 ops in numpy order, then fp16 round.
  float y = 64.0f;
  volatile float x2 = 32.0f;
  int ib; memcpy(&ib, &y, 4);
  ib = 1597463007 - (ib >> 1);
  memcpy(&y, &ib, 4);
  volatile float t1 = x2 * y;
  volatile float t2 = t1 * y;
  volatile float t3 = 1.5f - t2;
  y = y * t3;
  const float scaling = fp16_round_host(y);
  const float scal2 = scaling * 1.4426950408889634f;  // * log2(e)

  const int ncast = (TGT * DIM + OD3 * DIM + DIM * DIM) / 8;
  cast_all<<<(ncast + 255) / 256, 256, 0, stream>>>(x, Win, Wout, xh, winh, wouth);
  gemm_qkv<<<384, 256, 0, stream>>>(xh, winh, qh, kg, vg);
  attn<<<512, 512, 0, stream>>>(qh, kg, vg, ctxh, scal2);
  gemm_out<<<512, 256, 0, stream>>>(ctxh, wouth, out);
}